// Round 1
// 368.046 us; speedup vs baseline: 1.1808x; 1.1808x over previous
//
#include <hip/hip_runtime.h>
#include <math.h>

#define N_NODES 50000
#define N_EDGES 800000
#define D_IN 128
#define D1 150
#define LD1 152   // h1 leading dim (16B-aligned rows; pad cols written 0)
#define D2 100
#define LDP 128   // p / ns leading dim (alignment; pad cols written 0, never read)
#define D_OUT 64
#define SLOT 64   // fixed bucket capacity per dst node; P(deg_in>64) ~ 1e-15 (Poisson 16)
#define HBLK 64   // histogram shards (deg_out via LDS atomics)
#define HBIN 12500  // 50000 bins packed 4 x u8 per int

#define LDS_K 40  // LDS k-stride (32 used + 8 pad) -> 80B rows, b128-conflict-free

using short8 = __attribute__((ext_vector_type(8))) short;   // 8 bf16 (4 VGPRs)
using f32x4  = __attribute__((ext_vector_type(4))) float;   // MFMA accumulator

__device__ __forceinline__ float elu(float v) { return v > 0.0f ? v : expm1f(v); }

// fp32 -> bf16 hi/lo split (round-to-nearest via +0x8000 trick).
// a ~= hi + lo with |a - hi - lo| ~ 2^-17 |a|; dropping lo*lo in the GEMM keeps
// per-product relative error ~2^-16.
__device__ __forceinline__ void split_bf16(float a, unsigned short& h, unsigned short& l) {
    unsigned int bits = __float_as_uint(a);
    unsigned int hb = (bits + 0x8000u) >> 16;
    h = (unsigned short)hb;
    float r = a - __uint_as_float(hb << 16);
    l = (unsigned short)((__float_as_uint(r) + 0x8000u) >> 16);
}

// split 16 fp32 -> two short8 hi + two short8 lo and store to LDS row (b128 x4)
__device__ __forceinline__ void split_store16(unsigned short* hrow, unsigned short* lrow,
                                              const float* vv) {
    short8 h0, h1v, l0, l1v;
#pragma unroll
    for (int i = 0; i < 8; ++i) {
        unsigned short hh, ll;
        split_bf16(vv[i], hh, ll);
        h0[i] = (short)hh; l0[i] = (short)ll;
    }
#pragma unroll
    for (int i = 0; i < 8; ++i) {
        unsigned short hh, ll;
        split_bf16(vv[8 + i], hh, ll);
        h1v[i] = (short)hh; l1v[i] = (short)ll;
    }
    *(short8*)(hrow) = h0;
    *(short8*)(hrow + 8) = h1v;
    *(short8*)(lrow) = l0;
    *(short8*)(lrow + 8) = l1v;
}

// ---------------- deg_out histogram via LDS atomics ----------------
__global__ __launch_bounds__(256) void hist_kernel(const int* __restrict__ src,
                                                   unsigned int* __restrict__ partial) {
    __shared__ unsigned int bins[HBIN];   // 50 KB
    int tid = threadIdx.x, b = blockIdx.x;
    for (int i = tid; i < HBIN; i += 256) bins[i] = 0u;
    __syncthreads();
    int e0 = b * (N_EDGES / HBLK);
    int e1 = e0 + (N_EDGES / HBLK);
    for (int e = e0 + tid; e < e1; e += 256) {
        int s = src[e];
        atomicAdd(&bins[s >> 2], 1u << ((s & 3) * 8));
    }
    __syncthreads();
    unsigned int* outp = partial + (size_t)b * HBIN;
    for (int i = tid; i < HBIN; i += 256) outp[i] = bins[i];
}

// ---------------- norm_out[n] = rsqrt(max(deg_out,1)) from packed partials ----------------
__global__ __launch_bounds__(256) void norm_kernel(const unsigned int* __restrict__ partial,
                                                   float* __restrict__ norm_out) {
    int i = blockIdx.x * blockDim.x + threadIdx.x;   // int position: 4 nodes
    if (i >= HBIN) return;
    unsigned int acc = 0;
#pragma unroll
    for (int h = 0; h < HBLK; ++h) acc += partial[(size_t)h * HBIN + i];
#pragma unroll
    for (int j = 0; j < 4; ++j) {
        unsigned int dg = (acc >> (j * 8)) & 0xFF;
        norm_out[i * 4 + j] = rsqrtf(fmaxf((float)dg, 1.0f));
    }
}

// ---------------- bucket fill: cursor atomic + slot store only (800k atomics) ----------------
__global__ void fill_kernel(const int* __restrict__ src, const int* __restrict__ dst,
                            int* __restrict__ cursor, unsigned short* __restrict__ slots) {
    int e = blockIdx.x * blockDim.x + threadIdx.x;
    if (e < N_EDGES) {
        int d = dst[e], s = src[e];
        int pos = atomicAdd(&cursor[d], 1);
        if (pos < SLOT) slots[d * SLOT + pos] = (unsigned short)s;
    }
}

// ---------------- gather 1: agg[n] = sum_e x[src[e]] * norm_out[src[e]] ----------------
__global__ __launch_bounds__(256) void gather_x(const float* __restrict__ x,
                                                const float* __restrict__ norm_out,
                                                const int* __restrict__ deg_in,
                                                const unsigned short* __restrict__ slots,
                                                float* __restrict__ agg) {
    int wave = threadIdx.x >> 6;
    int lane = threadIdx.x & 63;
    int half = lane >> 5;
    int c = lane & 31;
    int n = blockIdx.x * 4 + wave;
    if (n >= N_NODES) return;
    int beg = n * SLOT;
    int dg = deg_in[n]; if (dg > SLOT) dg = SLOT;
    int end = beg + dg;
    float4 acc = {0.0f, 0.0f, 0.0f, 0.0f};
    int e = beg + half;
    for (; e + 2 < end; e += 4) {
        int s0 = slots[e];
        int s1 = slots[e + 2];
        float w0 = norm_out[s0], w1 = norm_out[s1];
        float4 v0 = ((const float4*)(x + (size_t)s0 * D_IN))[c];
        float4 v1 = ((const float4*)(x + (size_t)s1 * D_IN))[c];
        acc.x += v0.x * w0 + v1.x * w1;
        acc.y += v0.y * w0 + v1.y * w1;
        acc.z += v0.z * w0 + v1.z * w1;
        acc.w += v0.w * w0 + v1.w * w1;
    }
    if (e < end) {
        int s = slots[e];
        float w = norm_out[s];
        float4 v = ((const float4*)(x + (size_t)s * D_IN))[c];
        acc.x += v.x * w; acc.y += v.y * w; acc.z += v.z * w; acc.w += v.w * w;
    }
    acc.x += __shfl_xor(acc.x, 32);
    acc.y += __shfl_xor(acc.y, 32);
    acc.z += __shfl_xor(acc.z, 32);
    acc.w += __shfl_xor(acc.w, 32);
    if (half == 0) ((float4*)(agg + (size_t)n * D_IN))[c] = acc;
}

// ---------------- gather 2: ns[n] = sum_e p[src[e]]  (only cols 0..99 read) ----------------
__global__ __launch_bounds__(256) void gather_p(const float* __restrict__ p,
                                                const int* __restrict__ deg_in,
                                                const unsigned short* __restrict__ slots,
                                                float* __restrict__ ns) {
    int wave = threadIdx.x >> 6;
    int lane = threadIdx.x & 63;
    int half = lane >> 5;
    int c = lane & 31;
    bool cv = c < D2 / 4;
    int n = blockIdx.x * 4 + wave;
    if (n >= N_NODES) return;
    int beg = n * SLOT;
    int dg = deg_in[n]; if (dg > SLOT) dg = SLOT;
    int end = beg + dg;
    float4 acc = {0.0f, 0.0f, 0.0f, 0.0f};
    if (cv) {
        int e = beg + half;
        for (; e + 2 < end; e += 4) {
            int s0 = slots[e];
            int s1 = slots[e + 2];
            float4 v0 = ((const float4*)(p + (size_t)s0 * LDP))[c];
            float4 v1 = ((const float4*)(p + (size_t)s1 * LDP))[c];
            acc.x += v0.x + v1.x;
            acc.y += v0.y + v1.y;
            acc.z += v0.z + v1.z;
            acc.w += v0.w + v1.w;
        }
        if (e < end) {
            int s = slots[e];
            float4 v = ((const float4*)(p + (size_t)s * LDP))[c];
            acc.x += v.x; acc.y += v.y; acc.z += v.z; acc.w += v.w;
        }
    }
    acc.x += __shfl_xor(acc.x, 32);
    acc.y += __shfl_xor(acc.y, 32);
    acc.z += __shfl_xor(acc.z, 32);
    acc.w += __shfl_xor(acc.w, 32);
    if (half == 0 && cv) ((float4*)(ns + (size_t)n * LDP))[c] = acc;
}

// ======================= split-bf16 MFMA GEMM =======================
// BM=128, BN=64, BK=32 (one 16x16x32 K-step). 4 waves as 2M x 2N; each wave owns
// 64x32 = 4x2 fragments. Per output fragment: 3 MFMAs (hh, lh, hl) -> fp32-split
// accuracy at bf16 MFMA rate. LDS rows padded 32->40 elems (80 B): every b128
// read/write lands 8 accesses/bank (the b128 floor) -> conflict-free.
// C/D layout (verified): col = lane&15, row = (lane>>4)*4 + reg.

template <int K, int KP, int NW, int LDA, int PRE, int EPI, int LDC>
__global__ __launch_bounds__(256, 2)
void gemm_mfma(const float* __restrict__ A, const float* __restrict__ W,
               const float* __restrict__ nsrc, const int* __restrict__ deg,
               const float* __restrict__ bstage, const float* __restrict__ bepi,
               float* __restrict__ C) {
    __shared__ __align__(16) unsigned short AsH[128][LDS_K];
    __shared__ __align__(16) unsigned short AsL[128][LDS_K];
    __shared__ __align__(16) unsigned short BsH[64][LDS_K];
    __shared__ __align__(16) unsigned short BsL[64][LDS_K];

    const int tid = threadIdx.x;
    const int m0 = blockIdx.x * 128;
    const int n0 = blockIdx.y * 64;

    // A staging: 2 threads per row, 16 contiguous k each (same global pattern as proven kernel)
    const int arow = tid >> 1;
    const int af = (tid & 1) * 16;
    const int grow = m0 + arow;
    // B staging: thread = one column of W, 8 k values (coalesced global, b128 LDS write)
    const int bn = tid & 63;
    const int bkg = tid >> 6;
    const int bcol = n0 + bn;
    // fragment coords
    const int wid = tid >> 6;
    const int lane = tid & 63;
    const int wm = (wid >> 1) * 64;
    const int wn = (wid & 1) * 32;
    const int fr = lane & 15;
    const int fg = lane >> 4;

    float invd = 1.0f;
    if (PRE) {
        int dv = (grow < N_NODES) ? deg[grow] : 1;
        invd = 1.0f / fmaxf((float)dv, 1.0f);
    }

    f32x4 acc[4][2];
#pragma unroll
    for (int i = 0; i < 4; ++i)
#pragma unroll
        for (int j = 0; j < 2; ++j) acc[i][j] = {0.0f, 0.0f, 0.0f, 0.0f};

    for (int k0 = 0; k0 < KP; k0 += 32) {
        __syncthreads();
        // ---- A tile -> split bf16 LDS ----
        if (grow < N_NODES && k0 + 32 <= K) {
            const float* ap = A + (size_t)grow * LDA + k0 + af;
            float vv[16];
            if (!PRE) {
                float4 v0 = *(const float4*)(ap + 0);
                float4 v1 = *(const float4*)(ap + 4);
                float4 v2 = *(const float4*)(ap + 8);
                float4 v3 = *(const float4*)(ap + 12);
                vv[0] = v0.x;  vv[1] = v0.y;  vv[2] = v0.z;  vv[3] = v0.w;
                vv[4] = v1.x;  vv[5] = v1.y;  vv[6] = v1.z;  vv[7] = v1.w;
                vv[8] = v2.x;  vv[9] = v2.y;  vv[10] = v2.z; vv[11] = v2.w;
                vv[12] = v3.x; vv[13] = v3.y; vv[14] = v3.z; vv[15] = v3.w;
            } else {
                const float* np = nsrc + (size_t)grow * LDP + k0 + af;
#pragma unroll
                for (int h = 0; h < 4; ++h) {
                    float4 a = *(const float4*)(ap + h * 4);
                    float4 nv = *(const float4*)(np + h * 4);
                    int kb = k0 + af + h * 4;
                    vv[h * 4 + 0] = elu(a.x + bstage[kb + 0] + nv.x * invd);
                    vv[h * 4 + 1] = elu(a.y + bstage[kb + 1] + nv.y * invd);
                    vv[h * 4 + 2] = elu(a.z + bstage[kb + 2] + nv.z * invd);
                    vv[h * 4 + 3] = elu(a.w + bstage[kb + 3] + nv.w * invd);
                }
            }
            split_store16(&AsH[arow][af], &AsL[arow][af], vv);
        } else {
#pragma unroll
            for (int i = 0; i < 16; ++i) {
                int k = k0 + af + i;
                float v = 0.0f;
                if (grow < N_NODES && k < K) {
                    if (!PRE) v = A[(size_t)grow * LDA + k];
                    else
                        v = elu(A[(size_t)grow * LDA + k] + bstage[k] +
                                nsrc[(size_t)grow * LDP + k] * invd);
                }
                unsigned short hh, ll;
                split_bf16(v, hh, ll);
                AsH[arow][af + i] = hh;
                AsL[arow][af + i] = ll;
            }
        }
        // ---- B tile -> split bf16 LDS (transposed: [n][k]) ----
        {
            short8 hh8, ll8;
#pragma unroll
            for (int kk = 0; kk < 8; ++kk) {
                int k = k0 + bkg * 8 + kk;
                float w = (k < K && bcol < NW) ? W[(size_t)k * NW + bcol] : 0.0f;
                unsigned short hh, ll;
                split_bf16(w, hh, ll);
                hh8[kk] = (short)hh; ll8[kk] = (short)ll;
            }
            *(short8*)&BsH[bn][bkg * 8] = hh8;
            *(short8*)&BsL[bn][bkg * 8] = ll8;
        }
        __syncthreads();
        // ---- fragments + MFMA ----
        short8 ah[4], al[4], bh[2], bl[2];
#pragma unroll
        for (int fi = 0; fi < 4; ++fi) {
            ah[fi] = *(const short8*)&AsH[wm + fi * 16 + fr][fg * 8];
            al[fi] = *(const short8*)&AsL[wm + fi * 16 + fr][fg * 8];
        }
#pragma unroll
        for (int fj = 0; fj < 2; ++fj) {
            bh[fj] = *(const short8*)&BsH[wn + fj * 16 + fr][fg * 8];
            bl[fj] = *(const short8*)&BsL[wn + fj * 16 + fr][fg * 8];
        }
#pragma unroll
        for (int fi = 0; fi < 4; ++fi)
#pragma unroll
            for (int fj = 0; fj < 2; ++fj) {
                acc[fi][fj] = __builtin_amdgcn_mfma_f32_16x16x32_bf16(ah[fi], bh[fj], acc[fi][fj], 0, 0, 0);
                acc[fi][fj] = __builtin_amdgcn_mfma_f32_16x16x32_bf16(al[fi], bh[fj], acc[fi][fj], 0, 0, 0);
                acc[fi][fj] = __builtin_amdgcn_mfma_f32_16x16x32_bf16(ah[fi], bl[fj], acc[fi][fj], 0, 0, 0);
            }
    }

    // ---- epilogue ----
#pragma unroll
    for (int fi = 0; fi < 4; ++fi) {
#pragma unroll
        for (int r = 0; r < 4; ++r) {
            int row = m0 + wm + fi * 16 + fg * 4 + r;
            if (row >= N_NODES) continue;
            float rmul = 1.0f;
            if (EPI == 1) rmul = rsqrtf(fmaxf((float)deg[row], 1.0f));
#pragma unroll
            for (int fj = 0; fj < 2; ++fj) {
                int col = n0 + wn + fj * 16 + fr;
                if (col >= LDC) continue;
                float v = 0.0f;
                if (col < NW) {
                    v = acc[fi][fj][r];
                    if (EPI == 1) v = elu(v * rmul + bepi[col]);
                    else if (EPI == 3) v = elu(v + bepi[col]);
                }
                C[(size_t)row * LDC + col] = v;
            }
        }
    }
}

// ---------------- gemm_dual (MFMA): [p | h2pre] = h1 @ [Wn | Ws] in ONE launch ----------------
// grid (391, 4): y<2 -> p tiles (LDP=128, zero-pad), y>=2 -> h2pre (LDC=100).
__global__ __launch_bounds__(256, 2)
void gemm_dual_mfma(const float* __restrict__ h1, const float* __restrict__ Wn,
                    const float* __restrict__ Ws, float* __restrict__ p,
                    float* __restrict__ h2pre) {
    __shared__ __align__(16) unsigned short AsH[128][LDS_K];
    __shared__ __align__(16) unsigned short AsL[128][LDS_K];
    __shared__ __align__(16) unsigned short BsH[64][LDS_K];
    __shared__ __align__(16) unsigned short BsL[64][LDS_K];

    const int tid = threadIdx.x;
    const int m0 = blockIdx.x * 128;
    const int yy = blockIdx.y;
    const int n0 = (yy & 1) * 64;
    const float* W = (yy < 2) ? Wn : Ws;

    const int arow = tid >> 1;
    const int af = (tid & 1) * 16;
    const int grow = m0 + arow;
    const int bn = tid & 63;
    const int bkg = tid >> 6;
    const int bcol = n0 + bn;
    const int wid = tid >> 6;
    const int lane = tid & 63;
    const int wm = (wid >> 1) * 64;
    const int wn = (wid & 1) * 32;
    const int fr = lane & 15;
    const int fg = lane >> 4;

    f32x4 acc[4][2];
#pragma unroll
    for (int i = 0; i < 4; ++i)
#pragma unroll
        for (int j = 0; j < 2; ++j) acc[i][j] = {0.0f, 0.0f, 0.0f, 0.0f};

    for (int k0 = 0; k0 < 160; k0 += 32) {
        __syncthreads();
        if (grow < N_NODES && k0 + 32 <= D1) {
            const float* ap = h1 + (size_t)grow * LD1 + k0 + af;
            float4 v0 = *(const float4*)(ap + 0);
            float4 v1 = *(const float4*)(ap + 4);
            float4 v2 = *(const float4*)(ap + 8);
            float4 v3 = *(const float4*)(ap + 12);
            float vv[16] = {v0.x, v0.y, v0.z, v0.w, v1.x, v1.y, v1.z, v1.w,
                            v2.x, v2.y, v2.z, v2.w, v3.x, v3.y, v3.z, v3.w};
            split_store16(&AsH[arow][af], &AsL[arow][af], vv);
        } else {
#pragma unroll
            for (int i = 0; i < 16; ++i) {
                int k = k0 + af + i;
                float v = (grow < N_NODES && k < D1) ? h1[(size_t)grow * LD1 + k] : 0.0f;
                unsigned short hh, ll;
                split_bf16(v, hh, ll);
                AsH[arow][af + i] = hh;
                AsL[arow][af + i] = ll;
            }
        }
        {
            short8 hh8, ll8;
#pragma unroll
            for (int kk = 0; kk < 8; ++kk) {
                int k = k0 + bkg * 8 + kk;
                float w = (k < D1 && bcol < D2) ? W[(size_t)k * D2 + bcol] : 0.0f;
                unsigned short hh, ll;
                split_bf16(w, hh, ll);
                hh8[kk] = (short)hh; ll8[kk] = (short)ll;
            }
            *(short8*)&BsH[bn][bkg * 8] = hh8;
            *(short8*)&BsL[bn][bkg * 8] = ll8;
        }
        __syncthreads();
        short8 ah[4], al[4], bh[2], bl[2];
#pragma unroll
        for (int fi = 0; fi < 4; ++fi) {
            ah[fi] = *(const short8*)&AsH[wm + fi * 16 + fr][fg * 8];
            al[fi] = *(const short8*)&AsL[wm + fi * 16 + fr][fg * 8];
        }
#pragma unroll
        for (int fj = 0; fj < 2; ++fj) {
            bh[fj] = *(const short8*)&BsH[wn + fj * 16 + fr][fg * 8];
            bl[fj] = *(const short8*)&BsL[wn + fj * 16 + fr][fg * 8];
        }
#pragma unroll
        for (int fi = 0; fi < 4; ++fi)
#pragma unroll
            for (int fj = 0; fj < 2; ++fj) {
                acc[fi][fj] = __builtin_amdgcn_mfma_f32_16x16x32_bf16(ah[fi], bh[fj], acc[fi][fj], 0, 0, 0);
                acc[fi][fj] = __builtin_amdgcn_mfma_f32_16x16x32_bf16(al[fi], bh[fj], acc[fi][fj], 0, 0, 0);
                acc[fi][fj] = __builtin_amdgcn_mfma_f32_16x16x32_bf16(ah[fi], bl[fj], acc[fi][fj], 0, 0, 0);
            }
    }

#pragma unroll
    for (int fi = 0; fi < 4; ++fi) {
#pragma unroll
        for (int r = 0; r < 4; ++r) {
            int row = m0 + wm + fi * 16 + fg * 4 + r;
            if (row >= N_NODES) continue;
#pragma unroll
            for (int fj = 0; fj < 2; ++fj) {
                int col = n0 + wn + fj * 16 + fr;
                float v = acc[fi][fj][r];
                if (yy < 2) {
                    // p: LDC=128, zero-pad cols [100,128)
                    p[(size_t)row * LDP + col] = (col < D2) ? v : 0.0f;
                } else {
                    if (col < D2) h2pre[(size_t)row * D2 + col] = v;
                }
            }
        }
    }
}

extern "C" void kernel_launch(void* const* d_in, const int* in_sizes, int n_in,
                              void* d_out, int out_size, void* d_ws, size_t ws_size,
                              hipStream_t stream) {
    const float* x  = (const float*)d_in[0];
    const int* src  = (const int*)d_in[1];
    const int* dst  = (const int*)d_in[2];
    const float* W1 = (const float*)d_in[3];
    const float* b1 = (const float*)d_in[4];
    const float* Wn = (const float*)d_in[5];
    const float* Ws = (const float*)d_in[6];
    const float* b2 = (const float*)d_in[7];
    const float* W3 = (const float*)d_in[8];
    const float* b3 = (const float*)d_in[9];
    float* out = (float*)d_out;

    // workspace (4B elements), total 21.5M = 86 MB (layout proven R13):
    char* wsb = (char*)d_ws;
    unsigned int* partial = (unsigned int*)wsb;
    int*   cursor     = (int*)wsb + 800000;          // becomes deg_in
    float* norm_out   = (float*)wsb + 850000;
    unsigned short* slots = (unsigned short*)((float*)wsb + 900000);
    float* agg        = (float*)wsb + 2500000;
    float* h1         = (float*)wsb + 8900000;
    float* h2pre      = (float*)wsb + 16500000;
    float* p          = agg;   // overlay: agg dead after gemm1
    float* ns         = h1;    // overlay: h1 dead after gemm_dual
    int*   deg_in     = cursor;

    hipMemsetAsync(cursor, 0, N_NODES * sizeof(int), stream);

    hist_kernel<<<HBLK, 256, 0, stream>>>(src, partial);
    fill_kernel<<<(N_EDGES + 255) / 256, 256, 0, stream>>>(src, dst, cursor, slots);
    norm_kernel<<<(HBIN + 255) / 256, 256, 0, stream>>>(partial, norm_out);
    gather_x<<<(N_NODES + 3) / 4, 256, 0, stream>>>(x, norm_out, deg_in, slots, agg);

    const int MB = (N_NODES + 127) / 128;   // 391
    // gemm1: h1 = elu(rsqrt(deg_in)*(agg @ W1) + b1)   [K=128, N=150 -> LD1=152]
    gemm_mfma<128, 128, 150, 128, 0, 1, LD1><<<dim3(MB, 3), 256, 0, stream>>>(
        agg, W1, nullptr, deg_in, nullptr, b1, h1);
    // dual: [p | h2pre] = h1 @ [Wn | Ws]  (one launch, 1564 blocks)
    gemm_dual_mfma<<<dim3(MB, 4), 256, 0, stream>>>(h1, Wn, Ws, p, h2pre);
    gather_p<<<(N_NODES + 3) / 4, 256, 0, stream>>>(p, deg_in, slots, ns);
    // gemm3: out = elu( elu(h2pre + b2 + ns/deg) @ W3 + b3 )   [K=100, N=64]
    gemm_mfma<100, 128, 64, 100, 1, 3, D_OUT><<<dim3(MB, 1), 256, 0, stream>>>(
        h2pre, W3, ns, deg_in, b2, b3, out);
}